// Round 4
// baseline (622.965 us; speedup 1.0000x reference)
//
#include <hip/hip_runtime.h>

// ---------------------------------------------------------------------------
// GraphSAGE 2-layer (mean aggr) + linear classifier, fp32, N=100K, D=64, E=16N
// R8: lin layers were grid-starved (R7 counters: 127us, VALUBusy 16%, occ 17%
//  = 391 blocks -> 6 waves/CU; VALU floor is ~10us). Split the 64 outputs
//  into 4 slices of 16 across blockIdx.y -> 1564 blocks (~24 waves/CU).
//  Inputs re-read 4x but L2/L3-resident; each slice writes exactly one 64B
//  line per node row. lin2 classifier: slices write partial (p0,p1) to a
//  part[4][n][2] buffer (aliased onto dead col region), tiny combine adds bc.
// Rest unchanged from R7 (4-pass scatter, 16-deep wave-per-node aggregate).
// ---------------------------------------------------------------------------

#define SCAN_BS 1024
#define SCATTER_PASSES 4
#define JSPLIT 4   // output-feature slices per lin layer
#define JW 16      // 64 / JSPLIT outputs per slice

__global__ void zero_i32_kernel(int* __restrict__ p, int n) {
  int i = blockIdx.x * blockDim.x + threadIdx.x;
  if (i < n) p[i] = 0;
}

__global__ void hist_kernel(const int* __restrict__ dst, int* __restrict__ deg, int ne) {
  int e = blockIdx.x * blockDim.x + threadIdx.x;
  if (e < ne) atomicAdd(&deg[dst[e]], 1);
}

__device__ __forceinline__ int block_scan_inclusive_1024(int v, int* wsums) {
  int lane = threadIdx.x & 63;
  int wid = threadIdx.x >> 6;
  int s = v;
#pragma unroll
  for (int off = 1; off < 64; off <<= 1) {
    int t = __shfl_up(s, off);
    if (lane >= off) s += t;
  }
  if (lane == 63) wsums[wid] = s;
  __syncthreads();
  if (wid == 0) {
    int ws = (lane < 16) ? wsums[lane] : 0;
#pragma unroll
    for (int off = 1; off < 16; off <<= 1) {
      int t = __shfl_up(ws, off);
      if (lane >= off) ws += t;
    }
    if (lane < 16) wsums[lane] = ws;
  }
  __syncthreads();
  if (wid > 0) s += wsums[wid - 1];
  return s;
}

__global__ void __launch_bounds__(SCAN_BS) scan_a_kernel(const int* __restrict__ deg,
                                                         int* __restrict__ local_excl,
                                                         int* __restrict__ bsums, int n) {
  __shared__ int wsums[16];
  int i = blockIdx.x * SCAN_BS + threadIdx.x;
  int v = (i < n) ? deg[i] : 0;
  int inc = block_scan_inclusive_1024(v, wsums);
  if (i < n) local_excl[i] = inc - v;
  if (threadIdx.x == SCAN_BS - 1) bsums[blockIdx.x] = inc;
}

__global__ void __launch_bounds__(SCAN_BS) scan_b_kernel(const int* __restrict__ bsums,
                                                         int* __restrict__ boffs, int nb) {
  __shared__ int wsums[16];
  int v = ((int)threadIdx.x < nb) ? bsums[threadIdx.x] : 0;
  int inc = block_scan_inclusive_1024(v, wsums);
  if ((int)threadIdx.x < nb) boffs[threadIdx.x] = inc - v;
  if ((int)threadIdx.x == nb - 1) boffs[nb] = inc;
}

__global__ void scan_c_kernel(int* __restrict__ row_ptr, int* __restrict__ cursor,
                              const int* __restrict__ boffs, int n, int nb) {
  int i = blockIdx.x * blockDim.x + threadIdx.x;
  if (i < n) {
    int v = row_ptr[i] + boffs[i >> 10];
    row_ptr[i] = v;
    cursor[i] = v;
  }
  if (i == n) row_ptr[n] = boffs[nb];
}

__global__ void scatter_pass_kernel(const int* __restrict__ src, const int* __restrict__ dst,
                                    int* __restrict__ cursor, int* __restrict__ col,
                                    int ne, int lo, int hi) {
  int e = blockIdx.x * blockDim.x + threadIdx.x;
  if (e < ne) {
    int d = dst[e];
    if (d >= lo && d < hi) {
      int pos = atomicAdd(&cursor[d], 1);
      col[pos] = src[e];
    }
  }
}

// one wave per node, one feature per lane; scalarized col reads,
// 16 independent gathers in flight (mean deg = 16 -> ~1 latency round).
__global__ void __launch_bounds__(256) aggregate_kernel(const float* __restrict__ xin,
                                                        const int* __restrict__ row_ptr,
                                                        const int* __restrict__ col,
                                                        float* __restrict__ outp, int n) {
  int gwave = (blockIdx.x * 256 + threadIdx.x) >> 6;
  int lane = threadIdx.x & 63;
  if (gwave >= n) return;
  int m = __builtin_amdgcn_readfirstlane(gwave);
  int start = row_ptr[m];
  int end = row_ptr[m + 1];
  float a[16];
#pragma unroll
  for (int i = 0; i < 16; ++i) a[i] = 0.f;
  int e = start;
  for (; e + 16 <= end; e += 16) {
    int c[16];
#pragma unroll
    for (int i = 0; i < 16; ++i) c[i] = col[e + i];
#pragma unroll
    for (int i = 0; i < 16; ++i) a[i] += xin[(size_t)c[i] * 64 + lane];
  }
  for (; e + 4 <= end; e += 4) {
    int c0 = col[e + 0], c1 = col[e + 1], c2 = col[e + 2], c3 = col[e + 3];
    a[0] += xin[(size_t)c0 * 64 + lane];
    a[1] += xin[(size_t)c1 * 64 + lane];
    a[2] += xin[(size_t)c2 * 64 + lane];
    a[3] += xin[(size_t)c3 * 64 + lane];
  }
  for (; e < end; ++e) a[0] += xin[(size_t)col[e] * 64 + lane];
#pragma unroll
  for (int i = 8; i > 0; i >>= 1)
#pragma unroll
    for (int j = 0; j < i; ++j) a[j] += a[j + i];
  int d = end - start;
  float inv = 1.0f / (float)((d > 0) ? d : 1);
  outp[(size_t)m * 64 + lane] = a[0] * inv;
}

// out[:, jbase:jbase+16] = relu(agg @ Wl + b + xin @ Wr) slice.
// thread-per-node, blockIdx.y = output slice; uniform weight s_loads.
__global__ void __launch_bounds__(256) lin_relu_kernel(const float* __restrict__ agg,
                                                       const float* __restrict__ xin,
                                                       const float* __restrict__ Wl,
                                                       const float* __restrict__ bias,
                                                       const float* __restrict__ Wr,
                                                       float* __restrict__ outp, int n) {
  int node = blockIdx.x * 256 + threadIdx.x;
  if (node >= n) return;
  int jbase = blockIdx.y * JW;  // uniform
  const float4* ar = (const float4*)(agg + (size_t)node * 64);
  const float4* xr = (const float4*)(xin + (size_t)node * 64);
  const float* wl = Wl + jbase;
  const float* wr = Wr + jbase;
  float acc[JW];
#pragma unroll
  for (int j = 0; j < JW; ++j) acc[j] = bias[jbase + j];  // uniform -> s_load
#pragma unroll
  for (int k4 = 0; k4 < 16; ++k4) {
    float4 av = ar[k4];
    float4 xv = xr[k4];
#pragma unroll
    for (int j = 0; j < JW; ++j) {
      acc[j] = fmaf(av.x, wl[(k4 * 4 + 0) * 64 + j], acc[j]);
      acc[j] = fmaf(av.y, wl[(k4 * 4 + 1) * 64 + j], acc[j]);
      acc[j] = fmaf(av.z, wl[(k4 * 4 + 2) * 64 + j], acc[j]);
      acc[j] = fmaf(av.w, wl[(k4 * 4 + 3) * 64 + j], acc[j]);
      acc[j] = fmaf(xv.x, wr[(k4 * 4 + 0) * 64 + j], acc[j]);
      acc[j] = fmaf(xv.y, wr[(k4 * 4 + 1) * 64 + j], acc[j]);
      acc[j] = fmaf(xv.z, wr[(k4 * 4 + 2) * 64 + j], acc[j]);
      acc[j] = fmaf(xv.w, wr[(k4 * 4 + 3) * 64 + j], acc[j]);
    }
  }
  float4* op = (float4*)(outp + (size_t)node * 64 + jbase);
#pragma unroll
  for (int j4 = 0; j4 < JW / 4; ++j4) {
    float4 v;
    v.x = fmaxf(acc[j4 * 4 + 0], 0.f);
    v.y = fmaxf(acc[j4 * 4 + 1], 0.f);
    v.z = fmaxf(acc[j4 * 4 + 2], 0.f);
    v.w = fmaxf(acc[j4 * 4 + 3], 0.f);
    op[j4] = v;
  }
}

// slice of h2 = agg @ Wl + b + hin @ Wr (no relu); partial classifier dot
// over this slice's 16 dims -> part[slice][node][2].
__global__ void __launch_bounds__(256) lin2_part_kernel(const float* __restrict__ agg,
                                                        const float* __restrict__ hin,
                                                        const float* __restrict__ Wl,
                                                        const float* __restrict__ bias,
                                                        const float* __restrict__ Wr,
                                                        const float* __restrict__ Wc,
                                                        float* __restrict__ part, int n) {
  int node = blockIdx.x * 256 + threadIdx.x;
  if (node >= n) return;
  int jbase = blockIdx.y * JW;  // uniform
  const float4* ar = (const float4*)(agg + (size_t)node * 64);
  const float4* xr = (const float4*)(hin + (size_t)node * 64);
  const float* wl = Wl + jbase;
  const float* wr = Wr + jbase;
  float acc[JW];
#pragma unroll
  for (int j = 0; j < JW; ++j) acc[j] = bias[jbase + j];
#pragma unroll
  for (int k4 = 0; k4 < 16; ++k4) {
    float4 av = ar[k4];
    float4 xv = xr[k4];
#pragma unroll
    for (int j = 0; j < JW; ++j) {
      acc[j] = fmaf(av.x, wl[(k4 * 4 + 0) * 64 + j], acc[j]);
      acc[j] = fmaf(av.y, wl[(k4 * 4 + 1) * 64 + j], acc[j]);
      acc[j] = fmaf(av.z, wl[(k4 * 4 + 2) * 64 + j], acc[j]);
      acc[j] = fmaf(av.w, wl[(k4 * 4 + 3) * 64 + j], acc[j]);
      acc[j] = fmaf(xv.x, wr[(k4 * 4 + 0) * 64 + j], acc[j]);
      acc[j] = fmaf(xv.y, wr[(k4 * 4 + 1) * 64 + j], acc[j]);
      acc[j] = fmaf(xv.z, wr[(k4 * 4 + 2) * 64 + j], acc[j]);
      acc[j] = fmaf(xv.w, wr[(k4 * 4 + 3) * 64 + j], acc[j]);
    }
  }
  float p0 = 0.f, p1 = 0.f;
#pragma unroll
  for (int j = 0; j < JW; ++j) {
    p0 = fmaf(acc[j], Wc[(jbase + j) * 2 + 0], p0);  // uniform -> s_load
    p1 = fmaf(acc[j], Wc[(jbase + j) * 2 + 1], p1);
  }
  float2 o;
  o.x = p0;
  o.y = p1;
  *(float2*)(part + ((size_t)blockIdx.y * n + node) * 2) = o;
}

__global__ void cls_combine_kernel(const float* __restrict__ part,
                                   const float* __restrict__ bc,
                                   float* __restrict__ outp, int n) {
  int node = blockIdx.x * blockDim.x + threadIdx.x;
  if (node >= n) return;
  float p0 = bc[0], p1 = bc[1];
#pragma unroll
  for (int s = 0; s < JSPLIT; ++s) {
    float2 v = *(const float2*)(part + ((size_t)s * n + node) * 2);
    p0 += v.x;
    p1 += v.y;
  }
  float2 o;
  o.x = p0;
  o.y = p1;
  *(float2*)(outp + (size_t)node * 2) = o;
}

extern "C" void kernel_launch(void* const* d_in, const int* in_sizes, int n_in,
                              void* d_out, int out_size, void* d_ws, size_t ws_size,
                              hipStream_t stream) {
  const float* x   = (const float*)d_in[0];
  const int*   ei  = (const int*)d_in[1];
  const float* W1l = (const float*)d_in[2];
  const float* b1  = (const float*)d_in[3];
  const float* W1r = (const float*)d_in[4];
  const float* W2l = (const float*)d_in[5];
  const float* b2  = (const float*)d_in[6];
  const float* W2r = (const float*)d_in[7];
  const float* Wc  = (const float*)d_in[8];
  const float* bc  = (const float*)d_in[9];
  float* out = (float*)d_out;

  const int n  = in_sizes[0] / 64;   // 100000
  const int ne = in_sizes[1] / 2;    // 1600000
  const int* src = ei;
  const int* dst = ei + ne;

  char* ws = (char*)d_ws;
  size_t off = 0;
  auto carve = [&](size_t bytes) -> void* {
    void* p = ws + off;
    off += (bytes + 255) & ~(size_t)255;
    return p;
  };
  const int nb = (n + SCAN_BS - 1) / SCAN_BS;  // 98
  int* deg     = (int*)carve((size_t)n * 4);
  int* row_ptr = (int*)carve((size_t)(n + 1) * 4);
  int* cursor  = (int*)carve((size_t)n * 4);
  int* bsums   = (int*)carve((size_t)(nb + 1) * 4);
  int* boffs   = (int*)carve((size_t)(nb + 1) * 4);
  int* col     = (int*)carve((size_t)ne * 4);
  float* agg   = (float*)carve((size_t)n * 64 * 4);
  float* h     = (float*)carve((size_t)n * 64 * 4);
  // part[4][n][2] aliased onto col: col (6.4MB >= 3.2MB) is dead after the
  // second aggregate, and is rewritten by scatter before its next read.
  float* part  = (float*)col;
  (void)ws_size;

  zero_i32_kernel<<<(n + 255) / 256, 256, 0, stream>>>(deg, n);
  hist_kernel<<<(ne + 255) / 256, 256, 0, stream>>>(dst, deg, ne);

  scan_a_kernel<<<nb, SCAN_BS, 0, stream>>>(deg, row_ptr, bsums, n);
  scan_b_kernel<<<1, SCAN_BS, 0, stream>>>(bsums, boffs, nb);
  scan_c_kernel<<<(n + 256) / 256, 256, 0, stream>>>(row_ptr, cursor, boffs, n, nb);

  {
    int W = (n + SCATTER_PASSES - 1) / SCATTER_PASSES;
    for (int p = 0; p < SCATTER_PASSES; ++p) {
      int lo = p * W;
      int hi = (lo + W < n) ? (lo + W) : n;
      scatter_pass_kernel<<<(ne + 255) / 256, 256, 0, stream>>>(src, dst, cursor, col, ne, lo, hi);
    }
  }

  dim3 ling((n + 255) / 256, JSPLIT);
  aggregate_kernel<<<(n * 64 + 255) / 256, 256, 0, stream>>>(x, row_ptr, col, agg, n);
  lin_relu_kernel<<<ling, 256, 0, stream>>>(agg, x, W1l, b1, W1r, h, n);

  aggregate_kernel<<<(n * 64 + 255) / 256, 256, 0, stream>>>(h, row_ptr, col, agg, n);
  lin2_part_kernel<<<ling, 256, 0, stream>>>(agg, h, W2l, b2, W2r, Wc, part, n);
  cls_combine_kernel<<<(n + 255) / 256, 256, 0, stream>>>(part, bc, out, n);
}

// Round 5
// 586.853 us; speedup vs baseline: 1.0615x; 1.0615x over previous
//
#include <hip/hip_runtime.h>

// ---------------------------------------------------------------------------
// GraphSAGE 2-layer (mean aggr) + linear classifier, fp32, N=100K, D=64, E=16N
// R9: lin layers as LDS-tiled GEMMs.
//  R7: thread-per-node lin = latency-bound (occ 17%, 127us; VALU floor 10us).
//  R8: JSPLIT=4 raised occupancy but re-read inputs 4x uncoalesced ->
//      414MB L2-fill thrash, 123us. Both mappings lose on memory behavior.
//  Fix: block=256 threads stages a 64-node tile of m1 and x into LDS with
//  fully-coalesced float4 loads (each line consumed once, 4x LDS reuse),
//  lane=node / wave=16-output-slice, weights via wave-uniform s_loads.
//  1563 blocks -> ~16 waves/CU. gemm2 folds the classifier into its epilogue
//  (h2 never materialized). Workspace = R7's proven 58.5MB layout.
// CSR build + wave-per-node aggregate unchanged from R7.
// ---------------------------------------------------------------------------

#define SCAN_BS 1024
#define SCATTER_PASSES 4

__global__ void zero_i32_kernel(int* __restrict__ p, int n) {
  int i = blockIdx.x * blockDim.x + threadIdx.x;
  if (i < n) p[i] = 0;
}

__global__ void hist_kernel(const int* __restrict__ dst, int* __restrict__ deg, int ne) {
  int e = blockIdx.x * blockDim.x + threadIdx.x;
  if (e < ne) atomicAdd(&deg[dst[e]], 1);
}

__device__ __forceinline__ int block_scan_inclusive_1024(int v, int* wsums) {
  int lane = threadIdx.x & 63;
  int wid = threadIdx.x >> 6;
  int s = v;
#pragma unroll
  for (int off = 1; off < 64; off <<= 1) {
    int t = __shfl_up(s, off);
    if (lane >= off) s += t;
  }
  if (lane == 63) wsums[wid] = s;
  __syncthreads();
  if (wid == 0) {
    int ws = (lane < 16) ? wsums[lane] : 0;
#pragma unroll
    for (int off = 1; off < 16; off <<= 1) {
      int t = __shfl_up(ws, off);
      if (lane >= off) ws += t;
    }
    if (lane < 16) wsums[lane] = ws;
  }
  __syncthreads();
  if (wid > 0) s += wsums[wid - 1];
  return s;
}

__global__ void __launch_bounds__(SCAN_BS) scan_a_kernel(const int* __restrict__ deg,
                                                         int* __restrict__ local_excl,
                                                         int* __restrict__ bsums, int n) {
  __shared__ int wsums[16];
  int i = blockIdx.x * SCAN_BS + threadIdx.x;
  int v = (i < n) ? deg[i] : 0;
  int inc = block_scan_inclusive_1024(v, wsums);
  if (i < n) local_excl[i] = inc - v;
  if (threadIdx.x == SCAN_BS - 1) bsums[blockIdx.x] = inc;
}

__global__ void __launch_bounds__(SCAN_BS) scan_b_kernel(const int* __restrict__ bsums,
                                                         int* __restrict__ boffs, int nb) {
  __shared__ int wsums[16];
  int v = ((int)threadIdx.x < nb) ? bsums[threadIdx.x] : 0;
  int inc = block_scan_inclusive_1024(v, wsums);
  if ((int)threadIdx.x < nb) boffs[threadIdx.x] = inc - v;
  if ((int)threadIdx.x == nb - 1) boffs[nb] = inc;
}

__global__ void scan_c_kernel(int* __restrict__ row_ptr, int* __restrict__ cursor,
                              const int* __restrict__ boffs, int n, int nb) {
  int i = blockIdx.x * blockDim.x + threadIdx.x;
  if (i < n) {
    int v = row_ptr[i] + boffs[i >> 10];
    row_ptr[i] = v;
    cursor[i] = v;
  }
  if (i == n) row_ptr[n] = boffs[nb];
}

__global__ void scatter_pass_kernel(const int* __restrict__ src, const int* __restrict__ dst,
                                    int* __restrict__ cursor, int* __restrict__ col,
                                    int ne, int lo, int hi) {
  int e = blockIdx.x * blockDim.x + threadIdx.x;
  if (e < ne) {
    int d = dst[e];
    if (d >= lo && d < hi) {
      int pos = atomicAdd(&cursor[d], 1);
      col[pos] = src[e];
    }
  }
}

// one wave per node, one feature per lane; scalarized col reads,
// 16 independent gathers in flight (mean deg = 16 -> ~1 latency round).
__global__ void __launch_bounds__(256) aggregate_kernel(const float* __restrict__ xin,
                                                        const int* __restrict__ row_ptr,
                                                        const int* __restrict__ col,
                                                        float* __restrict__ outp, int n) {
  int gwave = (blockIdx.x * 256 + threadIdx.x) >> 6;
  int lane = threadIdx.x & 63;
  if (gwave >= n) return;
  int m = __builtin_amdgcn_readfirstlane(gwave);
  int start = row_ptr[m];
  int end = row_ptr[m + 1];
  float a[16];
#pragma unroll
  for (int i = 0; i < 16; ++i) a[i] = 0.f;
  int e = start;
  for (; e + 16 <= end; e += 16) {
    int c[16];
#pragma unroll
    for (int i = 0; i < 16; ++i) c[i] = col[e + i];
#pragma unroll
    for (int i = 0; i < 16; ++i) a[i] += xin[(size_t)c[i] * 64 + lane];
  }
  for (; e + 4 <= end; e += 4) {
    int c0 = col[e + 0], c1 = col[e + 1], c2 = col[e + 2], c3 = col[e + 3];
    a[0] += xin[(size_t)c0 * 64 + lane];
    a[1] += xin[(size_t)c1 * 64 + lane];
    a[2] += xin[(size_t)c2 * 64 + lane];
    a[3] += xin[(size_t)c3 * 64 + lane];
  }
  for (; e < end; ++e) a[0] += xin[(size_t)col[e] * 64 + lane];
#pragma unroll
  for (int i = 8; i > 0; i >>= 1)
#pragma unroll
    for (int j = 0; j < i; ++j) a[j] += a[j + i];
  int d = end - start;
  float inv = 1.0f / (float)((d > 0) ? d : 1);
  outp[(size_t)m * 64 + lane] = a[0] * inv;
}

// H = relu(A @ Wl + b + X @ Wr). Tiled: 64-node tile staged in LDS
// (coalesced float4), lane = node, wave = 16-output slice, weights s_load.
__global__ void __launch_bounds__(256) gemm_relu_kernel(const float* __restrict__ A,
                                                        const float* __restrict__ X,
                                                        const float* __restrict__ Wl,
                                                        const float* __restrict__ bias,
                                                        const float* __restrict__ Wr,
                                                        float* __restrict__ H, int n) {
  __shared__ float At[64][65];
  __shared__ float Xt[64][65];
  int t = threadIdx.x;
  int l = t & 63, w = t >> 6;
  int node0 = blockIdx.x * 64;
#pragma unroll
  for (int i = 0; i < 4; ++i) {
    int f4 = i * 256 + t;   // 0..1023 float4 slots over [64][16]
    int r = f4 >> 4;
    int c4 = f4 & 15;
    int nd = node0 + r;
    float4 av, xv;
    if (nd < n) {
      av = ((const float4*)(A + (size_t)nd * 64))[c4];
      xv = ((const float4*)(X + (size_t)nd * 64))[c4];
    } else {
      av = make_float4(0.f, 0.f, 0.f, 0.f);
      xv = av;
    }
    At[r][c4 * 4 + 0] = av.x; At[r][c4 * 4 + 1] = av.y;
    At[r][c4 * 4 + 2] = av.z; At[r][c4 * 4 + 3] = av.w;
    Xt[r][c4 * 4 + 0] = xv.x; Xt[r][c4 * 4 + 1] = xv.y;
    Xt[r][c4 * 4 + 2] = xv.z; Xt[r][c4 * 4 + 3] = xv.w;
  }
  __syncthreads();
  int jb = w * 16;  // wave-uniform output slice
  float acc[16];
#pragma unroll
  for (int j = 0; j < 16; ++j) acc[j] = bias[jb + j];  // uniform -> s_load
#pragma unroll 8
  for (int k = 0; k < 64; ++k) {
    float a = At[l][k];   // bank (l+k)%32: conflict-free
    float xv = Xt[l][k];
#pragma unroll
    for (int j = 0; j < 16; ++j) {
      acc[j] = fmaf(a, Wl[k * 64 + jb + j], acc[j]);   // uniform -> s_load
      acc[j] = fmaf(xv, Wr[k * 64 + jb + j], acc[j]);
    }
  }
  int nd = node0 + l;
  if (nd < n) {
    float4* op = (float4*)(H + (size_t)nd * 64 + jb);  // one 64B line per lane
#pragma unroll
    for (int j4 = 0; j4 < 4; ++j4) {
      float4 v;
      v.x = fmaxf(acc[j4 * 4 + 0], 0.f);
      v.y = fmaxf(acc[j4 * 4 + 1], 0.f);
      v.z = fmaxf(acc[j4 * 4 + 2], 0.f);
      v.w = fmaxf(acc[j4 * 4 + 3], 0.f);
      op[j4] = v;
    }
  }
}

// out = (A @ Wl + b + X @ Wr) @ Wc + bc  -> [n,2]; h2 never materialized.
// Same tiling as gemm_relu; per-wave partial classifier dots combined in LDS.
__global__ void __launch_bounds__(256) gemm_cls_kernel(const float* __restrict__ A,
                                                       const float* __restrict__ X,
                                                       const float* __restrict__ Wl,
                                                       const float* __restrict__ bias,
                                                       const float* __restrict__ Wr,
                                                       const float* __restrict__ Wc,
                                                       const float* __restrict__ bc,
                                                       float* __restrict__ outp, int n) {
  __shared__ float At[64][65];
  __shared__ float Xt[64][65];
  __shared__ float pp[4][64][2];
  int t = threadIdx.x;
  int l = t & 63, w = t >> 6;
  int node0 = blockIdx.x * 64;
#pragma unroll
  for (int i = 0; i < 4; ++i) {
    int f4 = i * 256 + t;
    int r = f4 >> 4;
    int c4 = f4 & 15;
    int nd = node0 + r;
    float4 av, xv;
    if (nd < n) {
      av = ((const float4*)(A + (size_t)nd * 64))[c4];
      xv = ((const float4*)(X + (size_t)nd * 64))[c4];
    } else {
      av = make_float4(0.f, 0.f, 0.f, 0.f);
      xv = av;
    }
    At[r][c4 * 4 + 0] = av.x; At[r][c4 * 4 + 1] = av.y;
    At[r][c4 * 4 + 2] = av.z; At[r][c4 * 4 + 3] = av.w;
    Xt[r][c4 * 4 + 0] = xv.x; Xt[r][c4 * 4 + 1] = xv.y;
    Xt[r][c4 * 4 + 2] = xv.z; Xt[r][c4 * 4 + 3] = xv.w;
  }
  __syncthreads();
  int jb = w * 16;
  float acc[16];
#pragma unroll
  for (int j = 0; j < 16; ++j) acc[j] = bias[jb + j];
#pragma unroll 8
  for (int k = 0; k < 64; ++k) {
    float a = At[l][k];
    float xv = Xt[l][k];
#pragma unroll
    for (int j = 0; j < 16; ++j) {
      acc[j] = fmaf(a, Wl[k * 64 + jb + j], acc[j]);
      acc[j] = fmaf(xv, Wr[k * 64 + jb + j], acc[j]);
    }
  }
  float p0 = 0.f, p1 = 0.f;
#pragma unroll
  for (int j = 0; j < 16; ++j) {
    p0 = fmaf(acc[j], Wc[(jb + j) * 2 + 0], p0);  // uniform -> s_load
    p1 = fmaf(acc[j], Wc[(jb + j) * 2 + 1], p1);
  }
  pp[w][l][0] = p0;
  pp[w][l][1] = p1;
  __syncthreads();
  if (w == 0) {
    int nd = node0 + l;
    if (nd < n) {
      float2 o;
      o.x = pp[0][l][0] + pp[1][l][0] + pp[2][l][0] + pp[3][l][0] + bc[0];
      o.y = pp[0][l][1] + pp[1][l][1] + pp[2][l][1] + pp[3][l][1] + bc[1];
      *(float2*)(outp + (size_t)nd * 2) = o;
    }
  }
}

extern "C" void kernel_launch(void* const* d_in, const int* in_sizes, int n_in,
                              void* d_out, int out_size, void* d_ws, size_t ws_size,
                              hipStream_t stream) {
  const float* x   = (const float*)d_in[0];
  const int*   ei  = (const int*)d_in[1];
  const float* W1l = (const float*)d_in[2];
  const float* b1  = (const float*)d_in[3];
  const float* W1r = (const float*)d_in[4];
  const float* W2l = (const float*)d_in[5];
  const float* b2  = (const float*)d_in[6];
  const float* W2r = (const float*)d_in[7];
  const float* Wc  = (const float*)d_in[8];
  const float* bc  = (const float*)d_in[9];
  float* out = (float*)d_out;

  const int n  = in_sizes[0] / 64;   // 100000
  const int ne = in_sizes[1] / 2;    // 1600000
  const int* src = ei;
  const int* dst = ei + ne;

  char* ws = (char*)d_ws;
  size_t off = 0;
  auto carve = [&](size_t bytes) -> void* {
    void* p = ws + off;
    off += (bytes + 255) & ~(size_t)255;
    return p;
  };
  const int nb = (n + SCAN_BS - 1) / SCAN_BS;  // 98
  int* deg     = (int*)carve((size_t)n * 4);
  int* row_ptr = (int*)carve((size_t)(n + 1) * 4);
  int* cursor  = (int*)carve((size_t)n * 4);
  int* bsums   = (int*)carve((size_t)(nb + 1) * 4);
  int* boffs   = (int*)carve((size_t)(nb + 1) * 4);
  int* col     = (int*)carve((size_t)ne * 4);
  float* m1    = (float*)carve((size_t)n * 64 * 4);  // mean buffer (both layers)
  float* h     = (float*)carve((size_t)n * 64 * 4);
  (void)ws_size;

  zero_i32_kernel<<<(n + 255) / 256, 256, 0, stream>>>(deg, n);
  hist_kernel<<<(ne + 255) / 256, 256, 0, stream>>>(dst, deg, ne);

  scan_a_kernel<<<nb, SCAN_BS, 0, stream>>>(deg, row_ptr, bsums, n);
  scan_b_kernel<<<1, SCAN_BS, 0, stream>>>(bsums, boffs, nb);
  scan_c_kernel<<<(n + 256) / 256, 256, 0, stream>>>(row_ptr, cursor, boffs, n, nb);

  {
    int W = (n + SCATTER_PASSES - 1) / SCATTER_PASSES;
    for (int p = 0; p < SCATTER_PASSES; ++p) {
      int lo = p * W;
      int hi = (lo + W < n) ? (lo + W) : n;
      scatter_pass_kernel<<<(ne + 255) / 256, 256, 0, stream>>>(src, dst, cursor, col, ne, lo, hi);
    }
  }

  const int gtiles = (n + 63) / 64;  // 1563
  aggregate_kernel<<<(n * 64 + 255) / 256, 256, 0, stream>>>(x, row_ptr, col, m1, n);
  gemm_relu_kernel<<<gtiles, 256, 0, stream>>>(m1, x, W1l, b1, W1r, h, n);

  aggregate_kernel<<<(n * 64 + 255) / 256, 256, 0, stream>>>(h, row_ptr, col, m1, n);
  gemm_cls_kernel<<<gtiles, 256, 0, stream>>>(m1, h, W2l, b2, W2r, Wc, bc, out, n);
}

// Round 8
// 442.960 us; speedup vs baseline: 1.4064x; 1.3248x over previous
//
#include <hip/hip_runtime.h>

// ---------------------------------------------------------------------------
// GraphSAGE 2-layer (mean aggr) + linear classifier, fp32, N=100K, D=64, E=16N
// R10 (2nd resubmit; R6 slot = GPUAcquisitionTimeout, R7 slot = container
//  failed twice -- both infra, kernel never executed):
//  register-tiled GEMM, zero scalar loads in the inner loop.
//  R7/R8/R9 lin variants ALL landed 118-127us despite occ 17/45/25% and
//  clean memory in R9 (FETCH 25MB) -> common factor = per-k weight s_loads
//  (8x s_load_dwordx4 + lgkmcnt waits ~1450 cyc/k). Fix: weights staged in
//  LDS, read per-lane via ds_read_b128; inputs in LDS with +65 pad and
//  conflict-free b32 frag reads. 256 thr = 16tx x 16ty, BM=128 BN=64 TM=8
//  TN=4, K=128 as two 64-phases reusing LDS (49KB -> 3 blocks/CU, grid 782
//  fully resident). Layer2 folds classifier via shfl_xor over tx.
// CSR build + wave-per-node aggregate unchanged from R7.
// ---------------------------------------------------------------------------

#define SCAN_BS 1024
#define SCATTER_PASSES 4

__global__ void zero_i32_kernel(int* __restrict__ p, int n) {
  int i = blockIdx.x * blockDim.x + threadIdx.x;
  if (i < n) p[i] = 0;
}

__global__ void hist_kernel(const int* __restrict__ dst, int* __restrict__ deg, int ne) {
  int e = blockIdx.x * blockDim.x + threadIdx.x;
  if (e < ne) atomicAdd(&deg[dst[e]], 1);
}

__device__ __forceinline__ int block_scan_inclusive_1024(int v, int* wsums) {
  int lane = threadIdx.x & 63;
  int wid = threadIdx.x >> 6;
  int s = v;
#pragma unroll
  for (int off = 1; off < 64; off <<= 1) {
    int t = __shfl_up(s, off);
    if (lane >= off) s += t;
  }
  if (lane == 63) wsums[wid] = s;
  __syncthreads();
  if (wid == 0) {
    int ws = (lane < 16) ? wsums[lane] : 0;
#pragma unroll
    for (int off = 1; off < 16; off <<= 1) {
      int t = __shfl_up(ws, off);
      if (lane >= off) ws += t;
    }
    if (lane < 16) wsums[lane] = ws;
  }
  __syncthreads();
  if (wid > 0) s += wsums[wid - 1];
  return s;
}

__global__ void __launch_bounds__(SCAN_BS) scan_a_kernel(const int* __restrict__ deg,
                                                         int* __restrict__ local_excl,
                                                         int* __restrict__ bsums, int n) {
  __shared__ int wsums[16];
  int i = blockIdx.x * SCAN_BS + threadIdx.x;
  int v = (i < n) ? deg[i] : 0;
  int inc = block_scan_inclusive_1024(v, wsums);
  if (i < n) local_excl[i] = inc - v;
  if (threadIdx.x == SCAN_BS - 1) bsums[blockIdx.x] = inc;
}

__global__ void __launch_bounds__(SCAN_BS) scan_b_kernel(const int* __restrict__ bsums,
                                                         int* __restrict__ boffs, int nb) {
  __shared__ int wsums[16];
  int v = ((int)threadIdx.x < nb) ? bsums[threadIdx.x] : 0;
  int inc = block_scan_inclusive_1024(v, wsums);
  if ((int)threadIdx.x < nb) boffs[threadIdx.x] = inc - v;
  if ((int)threadIdx.x == nb - 1) boffs[nb] = inc;
}

__global__ void scan_c_kernel(int* __restrict__ row_ptr, int* __restrict__ cursor,
                              const int* __restrict__ boffs, int n, int nb) {
  int i = blockIdx.x * blockDim.x + threadIdx.x;
  if (i < n) {
    int v = row_ptr[i] + boffs[i >> 10];
    row_ptr[i] = v;
    cursor[i] = v;
  }
  if (i == n) row_ptr[n] = boffs[nb];
}

__global__ void scatter_pass_kernel(const int* __restrict__ src, const int* __restrict__ dst,
                                    int* __restrict__ cursor, int* __restrict__ col,
                                    int ne, int lo, int hi) {
  int e = blockIdx.x * blockDim.x + threadIdx.x;
  if (e < ne) {
    int d = dst[e];
    if (d >= lo && d < hi) {
      int pos = atomicAdd(&cursor[d], 1);
      col[pos] = src[e];
    }
  }
}

// one wave per node, one feature per lane; scalarized col reads,
// 16 independent gathers in flight (mean deg = 16 -> ~1 latency round).
__global__ void __launch_bounds__(256) aggregate_kernel(const float* __restrict__ xin,
                                                        const int* __restrict__ row_ptr,
                                                        const int* __restrict__ col,
                                                        float* __restrict__ outp, int n) {
  int gwave = (blockIdx.x * 256 + threadIdx.x) >> 6;
  int lane = threadIdx.x & 63;
  if (gwave >= n) return;
  int m = __builtin_amdgcn_readfirstlane(gwave);
  int start = row_ptr[m];
  int end = row_ptr[m + 1];
  float a[16];
#pragma unroll
  for (int i = 0; i < 16; ++i) a[i] = 0.f;
  int e = start;
  for (; e + 16 <= end; e += 16) {
    int c[16];
#pragma unroll
    for (int i = 0; i < 16; ++i) c[i] = col[e + i];
#pragma unroll
    for (int i = 0; i < 16; ++i) a[i] += xin[(size_t)c[i] * 64 + lane];
  }
  for (; e + 4 <= end; e += 4) {
    int c0 = col[e + 0], c1 = col[e + 1], c2 = col[e + 2], c3 = col[e + 3];
    a[0] += xin[(size_t)c0 * 64 + lane];
    a[1] += xin[(size_t)c1 * 64 + lane];
    a[2] += xin[(size_t)c2 * 64 + lane];
    a[3] += xin[(size_t)c3 * 64 + lane];
  }
  for (; e < end; ++e) a[0] += xin[(size_t)col[e] * 64 + lane];
#pragma unroll
  for (int i = 8; i > 0; i >>= 1)
#pragma unroll
    for (int j = 0; j < i; ++j) a[j] += a[j + i];
  int d = end - start;
  float inv = 1.0f / (float)((d > 0) ? d : 1);
  outp[(size_t)m * 64 + lane] = a[0] * inv;
}

// ---- register-tiled GEMM pieces -------------------------------------------
// Block: 256 thr = 16tx (j, TN=4) x 16ty (nodes, TM=8). Tile 128x64.
// Phase p: acc += Mp @ Wp, Mp in {A,X}, Wp in {Wl,Wr}; LDS reused per phase.

#define GBM 128

__device__ __forceinline__ void gemm_phase(const float* __restrict__ M,
                                           const float* __restrict__ W,
                                           float (&Mt)[GBM][65], float (&Ws)[64][64],
                                           float4 (&acc)[8],
                                           int node0, int n, int tx, int ty, int t) {
  __syncthreads();  // previous phase's reads done before overwrite
#pragma unroll
  for (int i = 0; i < 8; ++i) {
    int f4 = i * 256 + t;          // 2048 float4 over [128][16]
    int r = f4 >> 4, c4 = f4 & 15;
    int nd = node0 + r;
    float4 v = make_float4(0.f, 0.f, 0.f, 0.f);
    if (nd < n) v = ((const float4*)(M + (size_t)nd * 64))[c4];
    Mt[r][c4 * 4 + 0] = v.x; Mt[r][c4 * 4 + 1] = v.y;  // banks (r+4c4+i)%32: 2-way
    Mt[r][c4 * 4 + 2] = v.z; Mt[r][c4 * 4 + 3] = v.w;
  }
#pragma unroll
  for (int i = 0; i < 4; ++i) {
    int f4 = i * 256 + t;          // 1024 float4 over [64][16]
    int k = f4 >> 4, c4 = f4 & 15;
    float4 v = ((const float4*)W)[f4];
    *(float4*)&Ws[k][c4 * 4] = v;  // row stride 256B aligned; 2-way banks
  }
  __syncthreads();
#pragma unroll 4
  for (int k = 0; k < 64; ++k) {
    float4 w4 = *(const float4*)&Ws[k][tx * 4];  // 16 chunks, 2-way: free
    float a[8];
#pragma unroll
    for (int m = 0; m < 8; ++m) a[m] = Mt[ty * 8 + m][k];  // banks ty*8+m+k: free
#pragma unroll
    for (int m = 0; m < 8; ++m) {
      acc[m].x = fmaf(a[m], w4.x, acc[m].x);
      acc[m].y = fmaf(a[m], w4.y, acc[m].y);
      acc[m].z = fmaf(a[m], w4.z, acc[m].z);
      acc[m].w = fmaf(a[m], w4.w, acc[m].w);
    }
  }
}

// H = relu(A @ Wl + b + X @ Wr)
__global__ void __launch_bounds__(256) gemm_relu_kernel(const float* __restrict__ A,
                                                        const float* __restrict__ X,
                                                        const float* __restrict__ Wl,
                                                        const float* __restrict__ bias,
                                                        const float* __restrict__ Wr,
                                                        float* __restrict__ H, int n) {
  __shared__ float Mt[GBM][65];
  __shared__ float Ws[64][64];
  int t = threadIdx.x;
  int tx = t & 15, ty = t >> 4;
  int node0 = blockIdx.x * GBM;
  float4 bv = *(const float4*)(bias + tx * 4);  // per-lane vector load
  float4 acc[8];
#pragma unroll
  for (int m = 0; m < 8; ++m) acc[m] = bv;
  gemm_phase(A, Wl, Mt, Ws, acc, node0, n, tx, ty, t);
  gemm_phase(X, Wr, Mt, Ws, acc, node0, n, tx, ty, t);
#pragma unroll
  for (int m = 0; m < 8; ++m) {
    int nd = node0 + ty * 8 + m;
    if (nd < n) {
      float4 v;
      v.x = fmaxf(acc[m].x, 0.f);
      v.y = fmaxf(acc[m].y, 0.f);
      v.z = fmaxf(acc[m].z, 0.f);
      v.w = fmaxf(acc[m].w, 0.f);
      ((float4*)(H + (size_t)nd * 64))[tx] = v;  // 16tx x 16B contiguous
    }
  }
}

// out = (A @ Wl + b + X @ Wr) @ Wc + bc; h2 never materialized.
// Per-thread partial classifier dot over its 4 j's; shfl_xor reduce over tx.
__global__ void __launch_bounds__(256) gemm_cls_kernel(const float* __restrict__ A,
                                                       const float* __restrict__ X,
                                                       const float* __restrict__ Wl,
                                                       const float* __restrict__ bias,
                                                       const float* __restrict__ Wr,
                                                       const float* __restrict__ Wc,
                                                       const float* __restrict__ bc,
                                                       float* __restrict__ outp, int n) {
  __shared__ float Mt[GBM][65];
  __shared__ float Ws[64][64];
  int t = threadIdx.x;
  int tx = t & 15, ty = t >> 4;
  int node0 = blockIdx.x * GBM;
  float4 bv = *(const float4*)(bias + tx * 4);
  float4 acc[8];
#pragma unroll
  for (int m = 0; m < 8; ++m) acc[m] = bv;
  gemm_phase(A, Wl, Mt, Ws, acc, node0, n, tx, ty, t);
  gemm_phase(X, Wr, Mt, Ws, acc, node0, n, tx, ty, t);
  // classifier weights for this thread's j-slice (per-lane vector loads)
  float2 wc0 = *(const float2*)(Wc + (tx * 4 + 0) * 2);
  float2 wc1 = *(const float2*)(Wc + (tx * 4 + 1) * 2);
  float2 wc2 = *(const float2*)(Wc + (tx * 4 + 2) * 2);
  float2 wc3 = *(const float2*)(Wc + (tx * 4 + 3) * 2);
  float b0 = bc[0], b1 = bc[1];
#pragma unroll
  for (int m = 0; m < 8; ++m) {
    float p0 = acc[m].x * wc0.x + acc[m].y * wc1.x + acc[m].z * wc2.x + acc[m].w * wc3.x;
    float p1 = acc[m].x * wc0.y + acc[m].y * wc1.y + acc[m].z * wc2.y + acc[m].w * wc3.y;
    // reduce across the 16 tx lanes (lane = ty*16+tx -> xor on bits 0..3)
#pragma unroll
    for (int off = 1; off < 16; off <<= 1) {
      p0 += __shfl_xor(p0, off);
      p1 += __shfl_xor(p1, off);
    }
    if (tx == 0) {
      int nd = node0 + ty * 8 + m;
      if (nd < n) {
        float2 o;
        o.x = p0 + b0;
        o.y = p1 + b1;
        *(float2*)(outp + (size_t)nd * 2) = o;
      }
    }
  }
}

extern "C" void kernel_launch(void* const* d_in, const int* in_sizes, int n_in,
                              void* d_out, int out_size, void* d_ws, size_t ws_size,
                              hipStream_t stream) {
  const float* x   = (const float*)d_in[0];
  const int*   ei  = (const int*)d_in[1];
  const float* W1l = (const float*)d_in[2];
  const float* b1  = (const float*)d_in[3];
  const float* W1r = (const float*)d_in[4];
  const float* W2l = (const float*)d_in[5];
  const float* b2  = (const float*)d_in[6];
  const float* W2r = (const float*)d_in[7];
  const float* Wc  = (const float*)d_in[8];
  const float* bc  = (const float*)d_in[9];
  float* out = (float*)d_out;

  const int n  = in_sizes[0] / 64;   // 100000
  const int ne = in_sizes[1] / 2;    // 1600000
  const int* src = ei;
  const int* dst = ei + ne;

  char* ws = (char*)d_ws;
  size_t off = 0;
  auto carve = [&](size_t bytes) -> void* {
    void* p = ws + off;
    off += (bytes + 255) & ~(size_t)255;
    return p;
  };
  const int nb = (n + SCAN_BS - 1) / SCAN_BS;  // 98
  int* deg     = (int*)carve((size_t)n * 4);
  int* row_ptr = (int*)carve((size_t)(n + 1) * 4);
  int* cursor  = (int*)carve((size_t)n * 4);
  int* bsums   = (int*)carve((size_t)(nb + 1) * 4);
  int* boffs   = (int*)carve((size_t)(nb + 1) * 4);
  int* col     = (int*)carve((size_t)ne * 4);
  float* m1    = (float*)carve((size_t)n * 64 * 4);  // mean buffer (both layers)
  float* h     = (float*)carve((size_t)n * 64 * 4);
  (void)ws_size;

  zero_i32_kernel<<<(n + 255) / 256, 256, 0, stream>>>(deg, n);
  hist_kernel<<<(ne + 255) / 256, 256, 0, stream>>>(dst, deg, ne);

  scan_a_kernel<<<nb, SCAN_BS, 0, stream>>>(deg, row_ptr, bsums, n);
  scan_b_kernel<<<1, SCAN_BS, 0, stream>>>(bsums, boffs, nb);
  scan_c_kernel<<<(n + 256) / 256, 256, 0, stream>>>(row_ptr, cursor, boffs, n, nb);

  {
    int W = (n + SCATTER_PASSES - 1) / SCATTER_PASSES;
    for (int p = 0; p < SCATTER_PASSES; ++p) {
      int lo = p * W;
      int hi = (lo + W < n) ? (lo + W) : n;
      scatter_pass_kernel<<<(ne + 255) / 256, 256, 0, stream>>>(src, dst, cursor, col, ne, lo, hi);
    }
  }

  const int gtiles = (n + GBM - 1) / GBM;  // 782
  aggregate_kernel<<<(n * 64 + 255) / 256, 256, 0, stream>>>(x, row_ptr, col, m1, n);
  gemm_relu_kernel<<<gtiles, 256, 0, stream>>>(m1, x, W1l, b1, W1r, h, n);

  aggregate_kernel<<<(n * 64 + 255) / 256, 256, 0, stream>>>(h, row_ptr, col, m1, n);
  gemm_cls_kernel<<<gtiles, 256, 0, stream>>>(m1, h, W2l, b2, W2r, Wc, bc, out, n);
}

// Round 9
// 327.700 us; speedup vs baseline: 1.9010x; 1.3517x over previous
//
#include <hip/hip_runtime.h>

// ---------------------------------------------------------------------------
// GraphSAGE 2-layer (mean aggr) + linear classifier, fp32, N=100K, D=64, E=16N
// R11: atomic-free CSR build (two-level LDS-cursor radix sort by dst).
//  R10 counters: hist_kernel 65us (1.6M global atomics @ 24.6G/s, 49.9MB
//  writeback amplification on a 400KB deg array); scatter 4-pass ~70us at the
//  same atomic rate => ~140us of the 443 is global-atomic-bound build.
//  Replace zero+hist+scan_c+scatter with: bucket_hist (LDS hist, dst>>7,
//  R6-proven) -> 2-level scan -> bucket_place (LDS cursors, R6-proven) ->
//  csr_bucket (NEW: per-bucket LDS hist of dst&127 + shuffle-scan -> row_ptr
//  + LDS-cursor place of src into col). Zero global atomics anywhere.
//  arr aliases m1 (dead until aggregate) => workspace stays ~59MB (proven).
// Aggregate (wave-per-node, 16-deep) + R10 register-tiled GEMMs unchanged.
// ---------------------------------------------------------------------------

#define SCAN_BS 1024
#define BUCKET_BITS 7
#define BUCKET_NODES 128
#define NBUCK_MAX 1024   // >= B = ceil(100000/128) = 782
#define EPB 8192         // edges per block in hist/place passes

// --- K1: per-block bucket histogram -> counts[k * NB + b] (bucket-major) ---
__global__ void __launch_bounds__(256) bucket_hist_kernel(const int* __restrict__ dst,
                                                          int* __restrict__ counts,
                                                          int ne, int B, int NB) {
  __shared__ int hist[NBUCK_MAX];
  for (int k = threadIdx.x; k < B; k += 256) hist[k] = 0;
  __syncthreads();
  int base = blockIdx.x * EPB;
#pragma unroll 4
  for (int i = 0; i < EPB / 256; ++i) {
    int e = base + i * 256 + threadIdx.x;
    if (e < ne) atomicAdd(&hist[dst[e] >> BUCKET_BITS], 1);
  }
  __syncthreads();
  for (int k = threadIdx.x; k < B; k += 256) counts[k * NB + blockIdx.x] = hist[k];
}

// --- 2-level scan (in-place exclusive over counts) ---
__device__ __forceinline__ int block_scan_inclusive_1024(int v, int* wsums) {
  int lane = threadIdx.x & 63;
  int wid = threadIdx.x >> 6;
  int s = v;
#pragma unroll
  for (int off = 1; off < 64; off <<= 1) {
    int t = __shfl_up(s, off);
    if (lane >= off) s += t;
  }
  if (lane == 63) wsums[wid] = s;
  __syncthreads();
  if (wid == 0) {
    int ws = (lane < 16) ? wsums[lane] : 0;
#pragma unroll
    for (int off = 1; off < 16; off <<= 1) {
      int t = __shfl_up(ws, off);
      if (lane >= off) ws += t;
    }
    if (lane < 16) wsums[lane] = ws;
  }
  __syncthreads();
  if (wid > 0) s += wsums[wid - 1];
  return s;
}

__global__ void __launch_bounds__(SCAN_BS) scan_a_inplace_kernel(int* __restrict__ data,
                                                                 int* __restrict__ bsums,
                                                                 int S) {
  __shared__ int wsums[16];
  int i = blockIdx.x * SCAN_BS + threadIdx.x;
  int v = (i < S) ? data[i] : 0;
  int inc = block_scan_inclusive_1024(v, wsums);
  if (i < S) data[i] = inc - v;  // exclusive, block-local
  if (threadIdx.x == SCAN_BS - 1) bsums[blockIdx.x] = inc;
}

__global__ void __launch_bounds__(SCAN_BS) scan_b_kernel(const int* __restrict__ bsums,
                                                         int* __restrict__ boffs, int nb) {
  __shared__ int wsums[16];
  int v = ((int)threadIdx.x < nb) ? bsums[threadIdx.x] : 0;
  int inc = block_scan_inclusive_1024(v, wsums);
  if ((int)threadIdx.x < nb) boffs[threadIdx.x] = inc - v;
  if ((int)threadIdx.x == nb - 1) boffs[nb] = inc;
}

__global__ void add_offs_kernel(int* __restrict__ v, const int* __restrict__ boffs, int S) {
  int i = blockIdx.x * blockDim.x + threadIdx.x;
  if (i < S) v[i] += boffs[i >> 10];
}

// --- K3: placement into bucket-grouped arr; LDS cursors, zero global atomics
__global__ void __launch_bounds__(256) bucket_place_kernel(const int* __restrict__ src,
                                                           const int* __restrict__ dst,
                                                           const int* __restrict__ counts,
                                                           int* __restrict__ arr,
                                                           int ne, int B, int NB) {
  __shared__ int cur[NBUCK_MAX];
  for (int k = threadIdx.x; k < B; k += 256) cur[k] = counts[k * NB + blockIdx.x];
  __syncthreads();
  int base = blockIdx.x * EPB;
#pragma unroll 4
  for (int i = 0; i < EPB / 256; ++i) {
    int e = base + i * 256 + threadIdx.x;
    if (e < ne) {
      int d = dst[e];
      int k = d >> BUCKET_BITS;
      int pos = atomicAdd(&cur[k], 1);  // LDS atomic, absolute output slot
      arr[pos] = (src[e] << BUCKET_BITS) | (d & (BUCKET_NODES - 1));
    }
  }
}

// --- K4 (new): per-bucket node-level CSR: row_ptr slice + col placement ---
__global__ void __launch_bounds__(256) csr_bucket_kernel(const int* __restrict__ arr,
                                                         const int* __restrict__ counts,
                                                         int* __restrict__ row_ptr,
                                                         int* __restrict__ col,
                                                         int n, int ne, int B, int NB) {
  __shared__ int hist[BUCKET_NODES];
  __shared__ int incl[BUCKET_NODES];
  __shared__ int cur[BUCKET_NODES];
  __shared__ int tot0s;
  int k = blockIdx.x;
  int tid = threadIdx.x;
  int start = counts[k * NB];
  int end = (k + 1 < B) ? counts[(k + 1) * NB] : ne;
  if (tid < BUCKET_NODES) hist[tid] = 0;
  __syncthreads();
  for (int e = start + tid; e < end; e += 256)
    atomicAdd(&hist[arr[e] & (BUCKET_NODES - 1)], 1);
  __syncthreads();
  // scan 128 counters: wave0 -> [0,64), wave1 -> [64,128)
  int lane = tid & 63, wid = tid >> 6;
  if (wid < 2) {
    int s = hist[wid * 64 + lane];
#pragma unroll
    for (int off = 1; off < 64; off <<= 1) {
      int t = __shfl_up(s, off);
      if (lane >= off) s += t;
    }
    incl[wid * 64 + lane] = s;
    if (wid == 0 && lane == 63) tot0s = s;
  }
  __syncthreads();
  if (tid < BUCKET_NODES) {
    int e0 = ((tid & 63) == 0) ? 0 : incl[tid - 1];
    if (tid >= 64) e0 += tot0s;
    int base = start + e0;
    cur[tid] = base;
    int node = k * BUCKET_NODES + tid;
    if (node < n) row_ptr[node] = base;
  }
  if (k == B - 1 && tid == 0) row_ptr[n] = ne;
  __syncthreads();
  for (int e = start + tid; e < end; e += 256) {
    int p = arr[e];
    int pos = atomicAdd(&cur[p & (BUCKET_NODES - 1)], 1);  // LDS atomic
    col[pos] = p >> BUCKET_BITS;
  }
}

// one wave per node, one feature per lane; scalarized col reads,
// 16 independent gathers in flight (mean deg = 16 -> ~1 latency round).
__global__ void __launch_bounds__(256) aggregate_kernel(const float* __restrict__ xin,
                                                        const int* __restrict__ row_ptr,
                                                        const int* __restrict__ col,
                                                        float* __restrict__ outp, int n) {
  int gwave = (blockIdx.x * 256 + threadIdx.x) >> 6;
  int lane = threadIdx.x & 63;
  if (gwave >= n) return;
  int m = __builtin_amdgcn_readfirstlane(gwave);
  int start = row_ptr[m];
  int end = row_ptr[m + 1];
  float a[16];
#pragma unroll
  for (int i = 0; i < 16; ++i) a[i] = 0.f;
  int e = start;
  for (; e + 16 <= end; e += 16) {
    int c[16];
#pragma unroll
    for (int i = 0; i < 16; ++i) c[i] = col[e + i];
#pragma unroll
    for (int i = 0; i < 16; ++i) a[i] += xin[(size_t)c[i] * 64 + lane];
  }
  for (; e + 4 <= end; e += 4) {
    int c0 = col[e + 0], c1 = col[e + 1], c2 = col[e + 2], c3 = col[e + 3];
    a[0] += xin[(size_t)c0 * 64 + lane];
    a[1] += xin[(size_t)c1 * 64 + lane];
    a[2] += xin[(size_t)c2 * 64 + lane];
    a[3] += xin[(size_t)c3 * 64 + lane];
  }
  for (; e < end; ++e) a[0] += xin[(size_t)col[e] * 64 + lane];
#pragma unroll
  for (int i = 8; i > 0; i >>= 1)
#pragma unroll
    for (int j = 0; j < i; ++j) a[j] += a[j + i];
  int d = end - start;
  float inv = 1.0f / (float)((d > 0) ? d : 1);
  outp[(size_t)m * 64 + lane] = a[0] * inv;
}

// ---- register-tiled GEMM (R10, zero scalar loads in the inner loop) -------
#define GBM 128

__device__ __forceinline__ void gemm_phase(const float* __restrict__ M,
                                           const float* __restrict__ W,
                                           float (&Mt)[GBM][65], float (&Ws)[64][64],
                                           float4 (&acc)[8],
                                           int node0, int n, int tx, int ty, int t) {
  __syncthreads();  // previous phase's reads done before overwrite
#pragma unroll
  for (int i = 0; i < 8; ++i) {
    int f4 = i * 256 + t;          // 2048 float4 over [128][16]
    int r = f4 >> 4, c4 = f4 & 15;
    int nd = node0 + r;
    float4 v = make_float4(0.f, 0.f, 0.f, 0.f);
    if (nd < n) v = ((const float4*)(M + (size_t)nd * 64))[c4];
    Mt[r][c4 * 4 + 0] = v.x; Mt[r][c4 * 4 + 1] = v.y;
    Mt[r][c4 * 4 + 2] = v.z; Mt[r][c4 * 4 + 3] = v.w;
  }
#pragma unroll
  for (int i = 0; i < 4; ++i) {
    int f4 = i * 256 + t;          // 1024 float4 over [64][16]
    int k = f4 >> 4, c4 = f4 & 15;
    float4 v = ((const float4*)W)[f4];
    *(float4*)&Ws[k][c4 * 4] = v;
  }
  __syncthreads();
#pragma unroll 4
  for (int k = 0; k < 64; ++k) {
    float4 w4 = *(const float4*)&Ws[k][tx * 4];
    float a[8];
#pragma unroll
    for (int m = 0; m < 8; ++m) a[m] = Mt[ty * 8 + m][k];
#pragma unroll
    for (int m = 0; m < 8; ++m) {
      acc[m].x = fmaf(a[m], w4.x, acc[m].x);
      acc[m].y = fmaf(a[m], w4.y, acc[m].y);
      acc[m].z = fmaf(a[m], w4.z, acc[m].z);
      acc[m].w = fmaf(a[m], w4.w, acc[m].w);
    }
  }
}

// H = relu(A @ Wl + b + X @ Wr)
__global__ void __launch_bounds__(256) gemm_relu_kernel(const float* __restrict__ A,
                                                        const float* __restrict__ X,
                                                        const float* __restrict__ Wl,
                                                        const float* __restrict__ bias,
                                                        const float* __restrict__ Wr,
                                                        float* __restrict__ H, int n) {
  __shared__ float Mt[GBM][65];
  __shared__ float Ws[64][64];
  int t = threadIdx.x;
  int tx = t & 15, ty = t >> 4;
  int node0 = blockIdx.x * GBM;
  float4 bv = *(const float4*)(bias + tx * 4);
  float4 acc[8];
#pragma unroll
  for (int m = 0; m < 8; ++m) acc[m] = bv;
  gemm_phase(A, Wl, Mt, Ws, acc, node0, n, tx, ty, t);
  gemm_phase(X, Wr, Mt, Ws, acc, node0, n, tx, ty, t);
#pragma unroll
  for (int m = 0; m < 8; ++m) {
    int nd = node0 + ty * 8 + m;
    if (nd < n) {
      float4 v;
      v.x = fmaxf(acc[m].x, 0.f);
      v.y = fmaxf(acc[m].y, 0.f);
      v.z = fmaxf(acc[m].z, 0.f);
      v.w = fmaxf(acc[m].w, 0.f);
      ((float4*)(H + (size_t)nd * 64))[tx] = v;
    }
  }
}

// out = (A @ Wl + b + X @ Wr) @ Wc + bc; h2 never materialized.
__global__ void __launch_bounds__(256) gemm_cls_kernel(const float* __restrict__ A,
                                                       const float* __restrict__ X,
                                                       const float* __restrict__ Wl,
                                                       const float* __restrict__ bias,
                                                       const float* __restrict__ Wr,
                                                       const float* __restrict__ Wc,
                                                       const float* __restrict__ bc,
                                                       float* __restrict__ outp, int n) {
  __shared__ float Mt[GBM][65];
  __shared__ float Ws[64][64];
  int t = threadIdx.x;
  int tx = t & 15, ty = t >> 4;
  int node0 = blockIdx.x * GBM;
  float4 bv = *(const float4*)(bias + tx * 4);
  float4 acc[8];
#pragma unroll
  for (int m = 0; m < 8; ++m) acc[m] = bv;
  gemm_phase(A, Wl, Mt, Ws, acc, node0, n, tx, ty, t);
  gemm_phase(X, Wr, Mt, Ws, acc, node0, n, tx, ty, t);
  float2 wc0 = *(const float2*)(Wc + (tx * 4 + 0) * 2);
  float2 wc1 = *(const float2*)(Wc + (tx * 4 + 1) * 2);
  float2 wc2 = *(const float2*)(Wc + (tx * 4 + 2) * 2);
  float2 wc3 = *(const float2*)(Wc + (tx * 4 + 3) * 2);
  float b0 = bc[0], b1 = bc[1];
#pragma unroll
  for (int m = 0; m < 8; ++m) {
    float p0 = acc[m].x * wc0.x + acc[m].y * wc1.x + acc[m].z * wc2.x + acc[m].w * wc3.x;
    float p1 = acc[m].x * wc0.y + acc[m].y * wc1.y + acc[m].z * wc2.y + acc[m].w * wc3.y;
#pragma unroll
    for (int off = 1; off < 16; off <<= 1) {
      p0 += __shfl_xor(p0, off);
      p1 += __shfl_xor(p1, off);
    }
    if (tx == 0) {
      int nd = node0 + ty * 8 + m;
      if (nd < n) {
        float2 o;
        o.x = p0 + b0;
        o.y = p1 + b1;
        *(float2*)(outp + (size_t)nd * 2) = o;
      }
    }
  }
}

extern "C" void kernel_launch(void* const* d_in, const int* in_sizes, int n_in,
                              void* d_out, int out_size, void* d_ws, size_t ws_size,
                              hipStream_t stream) {
  const float* x   = (const float*)d_in[0];
  const int*   ei  = (const int*)d_in[1];
  const float* W1l = (const float*)d_in[2];
  const float* b1  = (const float*)d_in[3];
  const float* W1r = (const float*)d_in[4];
  const float* W2l = (const float*)d_in[5];
  const float* b2  = (const float*)d_in[6];
  const float* W2r = (const float*)d_in[7];
  const float* Wc  = (const float*)d_in[8];
  const float* bc  = (const float*)d_in[9];
  float* out = (float*)d_out;

  const int n  = in_sizes[0] / 64;   // 100000
  const int ne = in_sizes[1] / 2;    // 1600000
  const int* src = ei;
  const int* dst = ei + ne;

  const int B  = (n + BUCKET_NODES - 1) >> BUCKET_BITS;  // 782
  const int NB = (ne + EPB - 1) / EPB;                   // 196
  const int S  = B * NB;                                 // 153272
  const int nsb = (S + SCAN_BS - 1) / SCAN_BS;           // 150 (<=1024)

  char* ws = (char*)d_ws;
  size_t off = 0;
  auto carve = [&](size_t bytes) -> void* {
    void* p = ws + off;
    off += (bytes + 255) & ~(size_t)255;
    return p;
  };
  int* counts  = (int*)carve((size_t)S * 4);
  int* bsums   = (int*)carve((size_t)(nsb + 1) * 4);
  int* boffs   = (int*)carve((size_t)(nsb + 1) * 4);
  int* col     = (int*)carve((size_t)ne * 4);
  int* row_ptr = (int*)carve((size_t)(n + 1) * 4);
  float* m1    = (float*)carve((size_t)n * 64 * 4);  // mean buffer (both layers)
  float* h     = (float*)carve((size_t)n * 64 * 4);
  // arr (6.4MB) aliases m1 (25.6MB): arr lives from bucket_place to
  // csr_bucket; m1 is first written by aggregate, which runs after.
  int* arr     = (int*)m1;
  (void)ws_size;

  bucket_hist_kernel<<<NB, 256, 0, stream>>>(dst, counts, ne, B, NB);
  scan_a_inplace_kernel<<<nsb, SCAN_BS, 0, stream>>>(counts, bsums, S);
  scan_b_kernel<<<1, SCAN_BS, 0, stream>>>(bsums, boffs, nsb);
  add_offs_kernel<<<(S + 255) / 256, 256, 0, stream>>>(counts, boffs, S);
  bucket_place_kernel<<<NB, 256, 0, stream>>>(src, dst, counts, arr, ne, B, NB);
  csr_bucket_kernel<<<B, 256, 0, stream>>>(arr, counts, row_ptr, col, n, ne, B, NB);

  const int gtiles = (n + GBM - 1) / GBM;  // 782
  aggregate_kernel<<<(n * 64 + 255) / 256, 256, 0, stream>>>(x, row_ptr, col, m1, n);
  gemm_relu_kernel<<<gtiles, 256, 0, stream>>>(m1, x, W1l, b1, W1r, h, n);

  aggregate_kernel<<<(n * 64 + 255) / 256, 256, 0, stream>>>(h, row_ptr, col, m1, n);
  gemm_cls_kernel<<<gtiles, 256, 0, stream>>>(m1, h, W2l, b2, W2r, Wc, bc, out, n);
}